// Round 3
// baseline (307.939 us; speedup 1.0000x reference)
//
#include <hip/hip_runtime.h>
#include <hip/hip_bf16.h>
#include <stdint.h>

// Problem constants: B=4, S=2048, D=1024, H=16, Dh=64
#define LOG2E 1.44269504088896340736f
#define SCL   (0.125f * LOG2E)   // folded into Q at the gemm epilogue

typedef __attribute__((ext_vector_type(8)))  short short8;     // 8 bf16 (4 VGPRs)
typedef __attribute__((ext_vector_type(16))) float floatx16;   // 32x32 C/D frag
typedef __attribute__((ext_vector_type(4)))  unsigned short ushort4v;

// global -> LDS direct DMA, 16B/lane. LDS dest is HW-fixed: wave-uniform base + lane*16.
#define GLP(g, l)                                                              \
    __builtin_amdgcn_global_load_lds(                                          \
        (const __attribute__((address_space(1))) void*)(g),                    \
        (__attribute__((address_space(3))) void*)(l), 16, 0, 0)

#if __has_builtin(__builtin_amdgcn_exp2f)
#define EXP2(x) __builtin_amdgcn_exp2f(x)   // raw v_exp_f32 (args bounded here)
#else
#define EXP2(x) exp2f(x)
#endif

static __device__ __forceinline__ unsigned short f2bf(float f) {
    union { float f; unsigned u; } v; v.f = f;
    unsigned r = v.u + 0x7FFFu + ((v.u >> 16) & 1u);  // RNE
    return (unsigned short)(r >> 16);
}

static __device__ __forceinline__ unsigned pack2bf(float a, float b) {
    __hip_bfloat162 h = __float22bfloat162_rn(make_float2(a, b));
    union { __hip_bfloat162 h; unsigned u; } c; c.h = h; return c.u;
}

// ------- merged fp32->bf16 convert: X | Wq|Wk|Wv | mask(xLOG2E) in one launch -------
__global__ __launch_bounds__(256) void cvt_all(const float* __restrict__ X,
                                               const float* __restrict__ Wq,
                                               const float* __restrict__ Wk,
                                               const float* __restrict__ Wv,
                                               const float* __restrict__ mask,
                                               unsigned short* __restrict__ xb,
                                               unsigned short* __restrict__ wb,
                                               float* __restrict__ maskl) {
    int i = blockIdx.x * 256 + threadIdx.x;   // 2097152 X + 786432 W + 2048 mask float4s
    if (i < 2097152) {
        float4 v = ((const float4*)X)[i];
        ushort4v o;
        o.x = f2bf(v.x); o.y = f2bf(v.y); o.z = f2bf(v.z); o.w = f2bf(v.w);
        ((ushort4v*)xb)[i] = o;
    } else if (i < 2883584) {
        int j = i - 2097152;
        const float* src; int k;
        if (j < 262144)      { src = Wq; k = j; }
        else if (j < 524288) { src = Wk; k = j - 262144; }
        else                 { src = Wv; k = j - 524288; }
        float4 v = ((const float4*)src)[k];
        ushort4v o;
        o.x = f2bf(v.x); o.y = f2bf(v.y); o.z = f2bf(v.z); o.w = f2bf(v.w);
        ((ushort4v*)wb)[j] = o;
    } else if (i < 2883584 + 2048) {
        int j = i - 2883584;
        float4 v = ((const float4*)mask)[j];
        ((float4*)maskl)[j] = make_float4(v.x * LOG2E, v.y * LOG2E,
                                          v.z * LOG2E, v.w * LOG2E);
    }
}

// ---------------- fused QKV projection GEMM (32x32x16 MFMA) ----------------
// C[m][n] = sum_k X[m][k] * W[n][k] + bias[n]   (NT gemm)
// M = 8192, N = 3072, K = 1024.  128x128 tile, BK=64, global_load_lds staging.
// Q scaled by SCL (folded softmax scale).  V stored transposed [64*64][2048] with
// key index bit2<->bit3 swapped (position permutation matching P's natural MFMA
// A-frag key order in the attention kernel -> no lane exchange needed there).
__global__ __launch_bounds__(256) void qkv_gemm(
        const unsigned short* __restrict__ X,   // [8192][1024] bf16
        const unsigned short* __restrict__ W,   // [3072][1024] bf16
        const float* __restrict__ bq, const float* __restrict__ bk,
        const float* __restrict__ bv,
        unsigned short* __restrict__ Qf,        // [8192][1024]  (pre-scaled by SCL)
        unsigned short* __restrict__ Kf,        // [8192][1024]
        unsigned short* __restrict__ Vt)        // [64*64][2048], key-permuted
{
    __shared__ __align__(16) unsigned short sh[17408];  // A(8192) B(8192); C-tile 128x136
    unsigned short* Ash = sh;
    unsigned short* Bsh = sh + 8192;

    const int tid  = threadIdx.x;
    const int lane = tid & 63;
    const int wv   = tid >> 6;
    const int q32  = lane & 31;
    const int hi   = lane >> 5;
    const int mBase = blockIdx.x * 128;
    const int nBase = blockIdx.y * 128;
    const int wm = (wv >> 1) * 64;
    const int wn = (wv & 1) * 64;

    floatx16 acc[2][2];
    acc[0][0] = 0.0f; acc[0][1] = 0.0f; acc[1][0] = 0.0f; acc[1][1] = 0.0f;

    const int sr = lane >> 3;            // 0..7 row-in-group
    const int kc = (lane & 7) ^ sr;      // swizzled 16B chunk

    for (int kb = 0; kb < 1024; kb += 64) {
        __syncthreads();
#pragma unroll
        for (int s = 0; s < 4; ++s) {
            const int seg = wv * 4 + s;          // row-group 0..15 (8 rows each)
            const int row = seg * 8 + sr;
            GLP(X + (size_t)(mBase + row) * 1024 + kb + kc * 8, Ash + seg * 512);
            GLP(W + (size_t)(nBase + row) * 1024 + kb + kc * 8, Bsh + seg * 512);
        }
        __syncthreads();
#pragma unroll
        for (int ks = 0; ks < 4; ++ks) {         // K=16 steps within BK=64
            short8 aF[2], bF[2];
#pragma unroll
            for (int mi = 0; mi < 2; ++mi) {
                const int R = wm + mi * 32 + q32;
                const int slot = (2 * ks + hi) ^ (R & 7);
                aF[mi] = *(const short8*)(Ash + (R >> 3) * 512 + (R & 7) * 64 + slot * 8);
            }
#pragma unroll
            for (int ni = 0; ni < 2; ++ni) {
                const int R = wn + ni * 32 + q32;
                const int slot = (2 * ks + hi) ^ (R & 7);
                bF[ni] = *(const short8*)(Bsh + (R >> 3) * 512 + (R & 7) * 64 + slot * 8);
            }
#pragma unroll
            for (int mi = 0; mi < 2; ++mi)
#pragma unroll
                for (int ni = 0; ni < 2; ++ni)
                    acc[mi][ni] = __builtin_amdgcn_mfma_f32_32x32x16_bf16(
                        aF[mi], bF[ni], acc[mi][ni], 0, 0, 0);
        }
    }

    // 32x32 C/D layout: col = lane&31, row = (r&3) + 8*(r>>2) + 4*hi (+ mi*32)
    if (blockIdx.y < 16) {
        // ---- Q or K: LDS transpose -> coalesced stores into [8192][1024] ----
        unsigned short* dst = (blockIdx.y < 8) ? Qf : Kf;
        const float* bias   = (blockIdx.y < 8) ? bq : bk;
        const float scl     = (blockIdx.y < 8) ? SCL : 1.0f;
        const int nb = nBase & 1023;
        float bj[2];
#pragma unroll
        for (int ni = 0; ni < 2; ++ni)
            bj[ni] = bias[nb + wn + ni * 32 + q32];
        __syncthreads();   // A/B LDS now dead for all waves
#pragma unroll
        for (int ni = 0; ni < 2; ++ni) {
            const int col = wn + ni * 32 + q32;
#pragma unroll
            for (int mi = 0; mi < 2; ++mi)
#pragma unroll
                for (int g = 0; g < 4; ++g) {
                    const int row0 = wm + mi * 32 + g * 8 + hi * 4;
#pragma unroll
                    for (int rr = 0; rr < 4; ++rr)
                        sh[(row0 + rr) * 136 + col] =
                            f2bf((acc[mi][ni][g * 4 + rr] + bj[ni]) * scl);
                }
        }
        __syncthreads();
        // 128 rows x 16 parts; 256 threads -> 16 rows/iter, 8 iters
#pragma unroll
        for (int it = 0; it < 8; ++it) {
            const int row  = it * 16 + (tid >> 4);
            const int part = tid & 15;
            short8 v = *(const short8*)(sh + row * 136 + part * 8);
            *(short8*)(dst + (size_t)(mBase + row) * 1024 + nb + part * 8) = v;
        }
    } else {
        // ---- V: transposed stores with key bits 2<->3 swapped (quad-aligned) ----
#pragma unroll
        for (int ni = 0; ni < 2; ++ni) {
            const int gn = nBase + wn + ni * 32 + q32;     // 2048..3071
            const int c  = gn & 1023;
            const int h  = c >> 6;
            const int d  = c & 63;
            const float bias = bv[c];
#pragma unroll
            for (int mi = 0; mi < 2; ++mi)
#pragma unroll
                for (int g = 0; g < 4; ++g) {
                    const int m0 = mBase + wm + mi * 32 + g * 8 + hi * 4;
                    const int b  = m0 >> 11;
                    const int s0 = m0 & 2047;
                    const int sp = (s0 & ~12) | ((s0 & 4) << 1) | ((s0 & 8) >> 1);
                    ushort4v pv;
#pragma unroll
                    for (int rr = 0; rr < 4; ++rr)
                        pv[rr] = f2bf(acc[mi][ni][g * 4 + rr] + bias);
                    *(ushort4v*)(Vt + (size_t)((b * 16 + h) * 64 + d) * 2048 + sp) = pv;
                }
        }
    }
}

// ---------------- flash attention: 32x32 MFMA, S^T, zero-exchange P ----------------
// Q pre-scaled by SCL; mask (xLOG2E) enters as the S-MFMA C-operand init.
// P's C/D output packs DIRECTLY into the PV A-frag (natural reg order): the key
// permutation this implies (swap positions [4-7]<->[8-11] per 16-key group) is
// pre-baked into Vt's key index by the gemm epilogue -> no shfl, no cndmask.
//
// R3: arithmetic-intensity fix. R0/R2 were LDS-READ-BOUND: each wave read the
// full 16KB K-tile + 16KB V-tile + mask per KV-tile (48 ds_read_b128/wave-tile,
// >= 8 cyc each) -> LDS pipe 3x oversubscribed vs MFMA (6144 vs 2066 cyc/CU-tile).
// K-frags (S^T A-operand) and V-frags (PV B-operand) depend only on the KEY, not
// the query -> 2 query-subtiles per wave (64 q/wave, 256 q/block) double MFMA+VALU
// per tile at CONSTANT LDS reads. LDS/work halves: now MFMA-bound (4132 vs 3072).
// Grid 512 = exactly 2 blocks/CU (dbuf LDS 66.6 KB), zero tail, prefetch kept.
__global__ __launch_bounds__(256, 2) void attn_kernel(
        const unsigned short* __restrict__ Qf,   // [8192][1024] bf16 (x SCL)
        const unsigned short* __restrict__ Kf,   // [8192][1024] bf16
        const unsigned short* __restrict__ VT,   // [64*64][2048] bf16, key-permuted
        const float* __restrict__ maskl,         // [4][2048], pre-scaled by LOG2E
        float* __restrict__ out)                 // [4][2048][1024]
{
    __shared__ __align__(16) unsigned short Ksh[2 * 128 * 64]; // 2 x (128 keys x 64 d)
    __shared__ __align__(16) unsigned short Vsh[2 * 64 * 128]; // 2 x (64 d x 128 keys)
    __shared__ __align__(16) float Msh[2 * 132];               // 2 x mask tile
    __shared__ __align__(16) float Lsh[256];                   // 1/l(q), end only

    const int tid  = threadIdx.x;
    const int lane = tid & 63;
    const int wv   = tid >> 6;
    const int q32  = lane & 31;
    const int hi   = lane >> 5;
    const int bh   = blockIdx.x & 63;
    const int qt   = blockIdx.x >> 6;                // 0..7
    const int b    = bh >> 4;
    const int h    = bh & 15;
    const int q0   = qt * 256 + wv * 64;             // wave owns 64 queries
    const int sw   = q32 & 7;                        // per-lane XOR swizzle key

    // Q as B-operand fragments for both q-subtiles, hoisted out of K-loop
    short8 bQ0[4], bQ1[4];
#pragma unroll
    for (int ks = 0; ks < 4; ++ks) {
        bQ0[ks] = *(const short8*)(Qf + (size_t)(b * 2048 + q0 + q32) * 1024
                                      + h * 64 + ks * 16 + hi * 8);
        bQ1[ks] = *(const short8*)(Qf + (size_t)(b * 2048 + q0 + 32 + q32) * 1024
                                      + h * 64 + ks * 16 + hi * 8);
    }

    floatx16 accO00 = 0.0f, accO01 = 0.0f;   // qsub0: d-lo, d-hi
    floatx16 accO10 = 0.0f, accO11 = 0.0f;   // qsub1
    float l0 = 0.0f, l1 = 0.0f;

    const unsigned short* gK = Kf + (size_t)(b * 2048) * 1024 + h * 64;
    const unsigned short* gV = VT + (size_t)(bh * 64) * 2048;
    const float* mrow = maskl + b * 2048;

    // hoisted, loop-invariant LDS read bases (imm offsets inside the loop)
    const unsigned short* kb4[4];
    const unsigned short* vb4[4];
#pragma unroll
    for (int ks = 0; ks < 4; ++ks) {
        const int cs = (2 * ks + hi) ^ sw;
        kb4[ks] = Ksh + q32 * 64 + cs * 8;
        vb4[ks] = Vsh + q32 * 128 + cs * 8;
    }

    // staging lane maps
    const int krr = lane >> 3;                 // K: row-in-group (8 rows/GLP)
    const int kcs = lane & 7;                  // K: slot
    const int vrr = lane >> 4;                 // V: row-in-group (4 rows/GLP)
    const int vcs = lane & 15;                 // V: slot (16/row)

    // stage tile (kbn) into buffer at ushort offset so / mask float offset mo
    auto STAGE = [&](int kbn, int so, int mo) {
#pragma unroll
        for (int s = 0; s < 4; ++s) {
            const int seg = wv * 4 + s;                       // 0..15
            const int rK  = seg * 8 + krr;                    // key row 0..127
            const int cK  = kcs ^ (rK & 7);
            GLP(gK + (size_t)(kbn + rK) * 1024 + cK * 8, Ksh + so + seg * 512);
            const int rV  = seg * 4 + vrr;                    // d row 0..63
            const int cV  = vcs ^ (rV & 7);
            GLP(gV + (size_t)rV * 2048 + kbn + cV * 8, Vsh + so + seg * 512);
        }
        if (tid < 32) GLP(mrow + kbn + lane * 4, Msh + mo);
    };

    // one KV tile: prefetch t+1 into the other buffer, compute t, drain+barrier
    auto TILE = [&](int kb, int ro, int mo, int so, int smo) {
        if (kb + 128 < 2048) STAGE(kb + 128, so, smo);
        const float* mb = Msh + mo + hi * 4;
#pragma unroll
        for (int half = 0; half < 2; ++half) {
#pragma unroll
            for (int mt = 0; mt < 2; ++mt) {
                // S^T tile: A = K (m=key 32), B = Q' (n=query 32), C init = mask
                floatx16 s0, s1;
#pragma unroll
                for (int a = 0; a < 4; ++a) {
                    float4 mv4 = *(const float4*)(mb + half * 64 + mt * 32 + a * 8);
                    s0[a * 4 + 0] = mv4.x; s0[a * 4 + 1] = mv4.y;
                    s0[a * 4 + 2] = mv4.z; s0[a * 4 + 3] = mv4.w;
                    s1[a * 4 + 0] = mv4.x; s1[a * 4 + 1] = mv4.y;
                    s1[a * 4 + 2] = mv4.z; s1[a * 4 + 3] = mv4.w;
                }
                short8 aK[4];
#pragma unroll
                for (int ks = 0; ks < 4; ++ks)
                    aK[ks] = *(const short8*)(kb4[ks] + ro + half * 4096 + mt * 2048);
                __builtin_amdgcn_s_setprio(1);
#pragma unroll
                for (int ks = 0; ks < 4; ++ks)
                    s0 = __builtin_amdgcn_mfma_f32_32x32x16_bf16(aK[ks], bQ0[ks], s0, 0, 0, 0);
#pragma unroll
                for (int ks = 0; ks < 4; ++ks)
                    s1 = __builtin_amdgcn_mfma_f32_32x32x16_bf16(aK[ks], bQ1[ks], s1, 0, 0, 0);
                __builtin_amdgcn_s_setprio(0);
                // V frags for this key-position (shared by BOTH q-subtiles)
                short8 bV00 = *(const short8*)(vb4[mt * 2 + 0] + ro + half * 64);
                short8 bV01 = *(const short8*)(vb4[mt * 2 + 0] + ro + 4096 + half * 64);
                short8 bV10 = *(const short8*)(vb4[mt * 2 + 1] + ro + half * 64);
                short8 bV11 = *(const short8*)(vb4[mt * 2 + 1] + ro + 4096 + half * 64);
                // ---- qsub0: p = exp2(s0), pack, PV ----
                {
                    unsigned u[8];
#pragma unroll
                    for (int a = 0; a < 4; ++a) {
                        float p0 = EXP2(s0[a * 4 + 0]);
                        float p1 = EXP2(s0[a * 4 + 1]);
                        float p2 = EXP2(s0[a * 4 + 2]);
                        float p3 = EXP2(s0[a * 4 + 3]);
                        l0 += (p0 + p1) + (p2 + p3);
                        u[2 * a]     = pack2bf(p0, p1);
                        u[2 * a + 1] = pack2bf(p2, p3);
                    }
                    union { unsigned uu[4]; short8 s; } aP;
                    aP.uu[0] = u[0]; aP.uu[1] = u[1]; aP.uu[2] = u[2]; aP.uu[3] = u[3];
                    __builtin_amdgcn_s_setprio(1);
                    accO00 = __builtin_amdgcn_mfma_f32_32x32x16_bf16(aP.s, bV00, accO00, 0, 0, 0);
                    accO01 = __builtin_amdgcn_mfma_f32_32x32x16_bf16(aP.s, bV01, accO01, 0, 0, 0);
                    __builtin_amdgcn_s_setprio(0);
                    aP.uu[0] = u[4]; aP.uu[1] = u[5]; aP.uu[2] = u[6]; aP.uu[3] = u[7];
                    __builtin_amdgcn_s_setprio(1);
                    accO00 = __builtin_amdgcn_mfma_f32_32x32x16_bf16(aP.s, bV10, accO00, 0, 0, 0);
                    accO01 = __builtin_amdgcn_mfma_f32_32x32x16_bf16(aP.s, bV11, accO01, 0, 0, 0);
                    __builtin_amdgcn_s_setprio(0);
                }
                // ---- qsub1 ----
                {
                    unsigned u[8];
#pragma unroll
                    for (int a = 0; a < 4; ++a) {
                        float p0 = EXP2(s1[a * 4 + 0]);
                        float p1 = EXP2(s1[a * 4 + 1]);
                        float p2 = EXP2(s1[a * 4 + 2]);
                        float p3 = EXP2(s1[a * 4 + 3]);
                        l1 += (p0 + p1) + (p2 + p3);
                        u[2 * a]     = pack2bf(p0, p1);
                        u[2 * a + 1] = pack2bf(p2, p3);
                    }
                    union { unsigned uu[4]; short8 s; } aP;
                    aP.uu[0] = u[0]; aP.uu[1] = u[1]; aP.uu[2] = u[2]; aP.uu[3] = u[3];
                    __builtin_amdgcn_s_setprio(1);
                    accO10 = __builtin_amdgcn_mfma_f32_32x32x16_bf16(aP.s, bV00, accO10, 0, 0, 0);
                    accO11 = __builtin_amdgcn_mfma_f32_32x32x16_bf16(aP.s, bV01, accO11, 0, 0, 0);
                    __builtin_amdgcn_s_setprio(0);
                    aP.uu[0] = u[4]; aP.uu[1] = u[5]; aP.uu[2] = u[6]; aP.uu[3] = u[7];
                    __builtin_amdgcn_s_setprio(1);
                    accO10 = __builtin_amdgcn_mfma_f32_32x32x16_bf16(aP.s, bV10, accO10, 0, 0, 0);
                    accO11 = __builtin_amdgcn_mfma_f32_32x32x16_bf16(aP.s, bV11, accO11, 0, 0, 0);
                    __builtin_amdgcn_s_setprio(0);
                }
            }
        }
        // prefetch (issued before ~4100 cyc of compute) has landed; drain is cheap.
        // Barrier also fences: everyone done reading buffer ro before next stage.
        asm volatile("s_waitcnt vmcnt(0) lgkmcnt(0)" ::: "memory");
        __builtin_amdgcn_s_barrier();
    };

    // prologue: stage tile 0 into buffer 0
    STAGE(0, 0, 0);
    asm volatile("s_waitcnt vmcnt(0)" ::: "memory");
    __builtin_amdgcn_s_barrier();

#pragma unroll 1
    for (int kb2 = 0; kb2 < 2048; kb2 += 256) {
        TILE(kb2,       0,    0,   8192, 132);   // read buf0, stage -> buf1
        TILE(kb2 + 128, 8192, 132, 0,    0);     // read buf1, stage -> buf0
    }

    // l(q): combine the two hi-halves, redistribute to row-indexed layout via Lsh
    l0 += __shfl_xor(l0, 32, 64);
    l1 += __shfl_xor(l1, 32, 64);
    if (lane < 32) {
        Lsh[wv * 64 + q32]      = 1.0f / l0;
        Lsh[wv * 64 + 32 + q32] = 1.0f / l1;
    }
    // wave-synchronous: same wave wrote Lsh; compiler orders via lgkmcnt
#pragma unroll
    for (int g = 0; g < 4; ++g) {
        float4 i0 = *(const float4*)(Lsh + wv * 64 + g * 8 + hi * 4);
        float4 i1 = *(const float4*)(Lsh + wv * 64 + 32 + g * 8 + hi * 4);
#pragma unroll
        for (int rr = 0; rr < 4; ++rr) {
            const int r   = g * 4 + rr;
            const int row = rr + 8 * g + 4 * hi;
            const float l0v = (rr == 0) ? i0.x : (rr == 1) ? i0.y
                            : (rr == 2) ? i0.z : i0.w;
            const float l1v = (rr == 0) ? i1.x : (rr == 1) ? i1.y
                            : (rr == 2) ? i1.z : i1.w;
            float* op0 = out + (size_t)(b * 2048 + q0 + row) * 1024 + h * 64 + q32;
            float* op1 = out + (size_t)(b * 2048 + q0 + 32 + row) * 1024 + h * 64 + q32;
            op0[0]  = accO00[r] * l0v;
            op0[32] = accO01[r] * l0v;
            op1[0]  = accO10[r] * l1v;
            op1[32] = accO11[r] * l1v;
        }
    }
}

// ---------------- launch ----------------
extern "C" void kernel_launch(void* const* d_in, const int* in_sizes, int n_in,
                              void* d_out, int out_size, void* d_ws, size_t ws_size,
                              hipStream_t stream) {
    const float* X    = (const float*)d_in[0];
    const float* mask = (const float*)d_in[1];
    const float* Wq   = (const float*)d_in[2];
    const float* bq   = (const float*)d_in[3];
    const float* Wk   = (const float*)d_in[4];
    const float* bk   = (const float*)d_in[5];
    const float* Wv   = (const float*)d_in[6];
    const float* bv   = (const float*)d_in[7];
    float* out = (float*)d_out;

    char* ws = (char*)d_ws;
    unsigned short* xb  = (unsigned short*)(ws);                // 8192*1024 bf16 (16MB)
    unsigned short* wb  = (unsigned short*)(ws + 16777216);     // 3072*1024 bf16 (6MB)
    unsigned short* qf  = (unsigned short*)(ws + 23068672);     // [8192][1024] (16MB)
    unsigned short* kf  = (unsigned short*)(ws + 39845888);     // [8192][1024] (16MB)
    unsigned short* vtb = (unsigned short*)(ws + 56623104);     // [64*64][2048] (16MB)
    float*          ml  = (float*)(ws + 73400320);              // [4][2048] (32KB)

    cvt_all<<<11272, 256, 0, stream>>>(X, Wq, Wk, Wv, mask, xb, wb, ml);

    qkv_gemm<<<dim3(64, 24), 256, 0, stream>>>(xb, wb, bq, bk, bv, qf, kf, vtb);

    attn_kernel<<<512, 256, 0, stream>>>(qf, kf, vtb, ml, out);
}

// Round 4
// 241.849 us; speedup vs baseline: 1.2733x; 1.2733x over previous
//
#include <hip/hip_runtime.h>
#include <hip/hip_bf16.h>
#include <stdint.h>

// Problem constants: B=4, S=2048, D=1024, H=16, Dh=64
#define LOG2E 1.44269504088896340736f
#define SCL   (0.125f * LOG2E)   // folded into Q at the gemm epilogue

typedef __attribute__((ext_vector_type(8)))  short short8;     // 8 bf16 (4 VGPRs)
typedef __attribute__((ext_vector_type(16))) float floatx16;   // 32x32 C/D frag
typedef __attribute__((ext_vector_type(4)))  unsigned short ushort4v;

// global -> LDS direct DMA, 16B/lane. LDS dest is HW-fixed: wave-uniform base + lane*16.
#define GLP(g, l)                                                              \
    __builtin_amdgcn_global_load_lds(                                          \
        (const __attribute__((address_space(1))) void*)(g),                    \
        (__attribute__((address_space(3))) void*)(l), 16, 0, 0)

#if __has_builtin(__builtin_amdgcn_exp2f)
#define EXP2(x) __builtin_amdgcn_exp2f(x)   // raw v_exp_f32 (args bounded here)
#else
#define EXP2(x) exp2f(x)
#endif

static __device__ __forceinline__ unsigned short f2bf(float f) {
    union { float f; unsigned u; } v; v.f = f;
    unsigned r = v.u + 0x7FFFu + ((v.u >> 16) & 1u);  // RNE
    return (unsigned short)(r >> 16);
}

static __device__ __forceinline__ unsigned pack2bf(float a, float b) {
    __hip_bfloat162 h = __float22bfloat162_rn(make_float2(a, b));
    union { __hip_bfloat162 h; unsigned u; } c; c.h = h; return c.u;
}

// ------- merged fp32->bf16 convert: X | Wq|Wk|Wv | mask(xLOG2E) in one launch -------
__global__ __launch_bounds__(256) void cvt_all(const float* __restrict__ X,
                                               const float* __restrict__ Wq,
                                               const float* __restrict__ Wk,
                                               const float* __restrict__ Wv,
                                               const float* __restrict__ mask,
                                               unsigned short* __restrict__ xb,
                                               unsigned short* __restrict__ wb,
                                               float* __restrict__ maskl) {
    int i = blockIdx.x * 256 + threadIdx.x;   // 2097152 X + 786432 W + 2048 mask float4s
    if (i < 2097152) {
        float4 v = ((const float4*)X)[i];
        ushort4v o;
        o.x = f2bf(v.x); o.y = f2bf(v.y); o.z = f2bf(v.z); o.w = f2bf(v.w);
        ((ushort4v*)xb)[i] = o;
    } else if (i < 2883584) {
        int j = i - 2097152;
        const float* src; int k;
        if (j < 262144)      { src = Wq; k = j; }
        else if (j < 524288) { src = Wk; k = j - 262144; }
        else                 { src = Wv; k = j - 524288; }
        float4 v = ((const float4*)src)[k];
        ushort4v o;
        o.x = f2bf(v.x); o.y = f2bf(v.y); o.z = f2bf(v.z); o.w = f2bf(v.w);
        ((ushort4v*)wb)[j] = o;
    } else if (i < 2883584 + 2048) {
        int j = i - 2883584;
        float4 v = ((const float4*)mask)[j];
        ((float4*)maskl)[j] = make_float4(v.x * LOG2E, v.y * LOG2E,
                                          v.z * LOG2E, v.w * LOG2E);
    }
}

// ---------------- fused QKV projection GEMM (32x32x16 MFMA) ----------------
// C[m][n] = sum_k X[m][k] * W[n][k] + bias[n]   (NT gemm)
// M = 8192, N = 3072, K = 1024.  128x128 tile, BK=64, global_load_lds staging.
// Q scaled by SCL (folded softmax scale).  V stored transposed [64*64][2048] with
// key index bit2<->bit3 swapped (position permutation matching P's natural MFMA
// A-frag key order in the attention kernel -> no lane exchange needed there).
__global__ __launch_bounds__(256) void qkv_gemm(
        const unsigned short* __restrict__ X,   // [8192][1024] bf16
        const unsigned short* __restrict__ W,   // [3072][1024] bf16
        const float* __restrict__ bq, const float* __restrict__ bk,
        const float* __restrict__ bv,
        unsigned short* __restrict__ Qf,        // [8192][1024]  (pre-scaled by SCL)
        unsigned short* __restrict__ Kf,        // [8192][1024]
        unsigned short* __restrict__ Vt)        // [64*64][2048], key-permuted
{
    __shared__ __align__(16) unsigned short sh[17408];  // A(8192) B(8192); C-tile 128x136
    unsigned short* Ash = sh;
    unsigned short* Bsh = sh + 8192;

    const int tid  = threadIdx.x;
    const int lane = tid & 63;
    const int wv   = tid >> 6;
    const int q32  = lane & 31;
    const int hi   = lane >> 5;
    const int mBase = blockIdx.x * 128;
    const int nBase = blockIdx.y * 128;
    const int wm = (wv >> 1) * 64;
    const int wn = (wv & 1) * 64;

    floatx16 acc[2][2];
    acc[0][0] = 0.0f; acc[0][1] = 0.0f; acc[1][0] = 0.0f; acc[1][1] = 0.0f;

    const int sr = lane >> 3;            // 0..7 row-in-group
    const int kc = (lane & 7) ^ sr;      // swizzled 16B chunk

    for (int kb = 0; kb < 1024; kb += 64) {
        __syncthreads();
#pragma unroll
        for (int s = 0; s < 4; ++s) {
            const int seg = wv * 4 + s;          // row-group 0..15 (8 rows each)
            const int row = seg * 8 + sr;
            GLP(X + (size_t)(mBase + row) * 1024 + kb + kc * 8, Ash + seg * 512);
            GLP(W + (size_t)(nBase + row) * 1024 + kb + kc * 8, Bsh + seg * 512);
        }
        __syncthreads();
#pragma unroll
        for (int ks = 0; ks < 4; ++ks) {         // K=16 steps within BK=64
            short8 aF[2], bF[2];
#pragma unroll
            for (int mi = 0; mi < 2; ++mi) {
                const int R = wm + mi * 32 + q32;
                const int slot = (2 * ks + hi) ^ (R & 7);
                aF[mi] = *(const short8*)(Ash + (R >> 3) * 512 + (R & 7) * 64 + slot * 8);
            }
#pragma unroll
            for (int ni = 0; ni < 2; ++ni) {
                const int R = wn + ni * 32 + q32;
                const int slot = (2 * ks + hi) ^ (R & 7);
                bF[ni] = *(const short8*)(Bsh + (R >> 3) * 512 + (R & 7) * 64 + slot * 8);
            }
#pragma unroll
            for (int mi = 0; mi < 2; ++mi)
#pragma unroll
                for (int ni = 0; ni < 2; ++ni)
                    acc[mi][ni] = __builtin_amdgcn_mfma_f32_32x32x16_bf16(
                        aF[mi], bF[ni], acc[mi][ni], 0, 0, 0);
        }
    }

    // 32x32 C/D layout: col = lane&31, row = (r&3) + 8*(r>>2) + 4*hi (+ mi*32)
    if (blockIdx.y < 16) {
        // ---- Q or K: LDS transpose -> coalesced stores into [8192][1024] ----
        unsigned short* dst = (blockIdx.y < 8) ? Qf : Kf;
        const float* bias   = (blockIdx.y < 8) ? bq : bk;
        const float scl     = (blockIdx.y < 8) ? SCL : 1.0f;
        const int nb = nBase & 1023;
        float bj[2];
#pragma unroll
        for (int ni = 0; ni < 2; ++ni)
            bj[ni] = bias[nb + wn + ni * 32 + q32];
        __syncthreads();   // A/B LDS now dead for all waves
#pragma unroll
        for (int ni = 0; ni < 2; ++ni) {
            const int col = wn + ni * 32 + q32;
#pragma unroll
            for (int mi = 0; mi < 2; ++mi)
#pragma unroll
                for (int g = 0; g < 4; ++g) {
                    const int row0 = wm + mi * 32 + g * 8 + hi * 4;
#pragma unroll
                    for (int rr = 0; rr < 4; ++rr)
                        sh[(row0 + rr) * 136 + col] =
                            f2bf((acc[mi][ni][g * 4 + rr] + bj[ni]) * scl);
                }
        }
        __syncthreads();
        // 128 rows x 16 parts; 256 threads -> 16 rows/iter, 8 iters
#pragma unroll
        for (int it = 0; it < 8; ++it) {
            const int row  = it * 16 + (tid >> 4);
            const int part = tid & 15;
            short8 v = *(const short8*)(sh + row * 136 + part * 8);
            *(short8*)(dst + (size_t)(mBase + row) * 1024 + nb + part * 8) = v;
        }
    } else {
        // ---- V: transposed stores with key bits 2<->3 swapped (quad-aligned) ----
#pragma unroll
        for (int ni = 0; ni < 2; ++ni) {
            const int gn = nBase + wn + ni * 32 + q32;     // 2048..3071
            const int c  = gn & 1023;
            const int h  = c >> 6;
            const int d  = c & 63;
            const float bias = bv[c];
#pragma unroll
            for (int mi = 0; mi < 2; ++mi)
#pragma unroll
                for (int g = 0; g < 4; ++g) {
                    const int m0 = mBase + wm + mi * 32 + g * 8 + hi * 4;
                    const int b  = m0 >> 11;
                    const int s0 = m0 & 2047;
                    const int sp = (s0 & ~12) | ((s0 & 4) << 1) | ((s0 & 8) >> 1);
                    ushort4v pv;
#pragma unroll
                    for (int rr = 0; rr < 4; ++rr)
                        pv[rr] = f2bf(acc[mi][ni][g * 4 + rr] + bias);
                    *(ushort4v*)(Vt + (size_t)((b * 16 + h) * 64 + d) * 2048 + sp) = pv;
                }
        }
    }
}

// ---------------- flash attention: 32x32 MFMA, S^T, zero-exchange P ----------------
// Q pre-scaled by SCL; mask (xLOG2E) enters as the S-MFMA C-operand init.
// P's C/D output packs DIRECTLY into the PV A-frag (natural reg order): the key
// permutation this implies (swap positions [4-7]<->[8-11] per 16-key group) is
// pre-baked into Vt's key index by the gemm epilogue -> no shfl, no cndmask.
//
// R4: 64 queries/wave (halves LDS reads per unit work -- R2 was LDS-read-bound,
// ~61us of 100us in ds_read_b128) with LIVENESS-BOUNDED codegen. R3's version
// spilled (WRITE_SIZE 113MB = 80MB scratch): full 4-subtile unroll let the
// scheduler keep 4 iterations of s0/s1/u/aK/bV in flight past the 256-reg cap.
// Fix: #pragma unroll 1 on the half-loop (compiler cannot interleave across
// non-unrolled iterations) + strict in-subtile order: aK -> S-MFMA(q0) ->
// S-MFMA(q1) [aK dies] -> exp/pack q0 -> exp/pack q1 [s dies] -> bV -> 8 PV.
// Peak live ~= accO 64 + bQ 32 + (aK+s0+s1) 48 + addr ~= 160 < 256.
// Grid 512 = exactly 2 blocks/CU (dbuf LDS 66.6 KB), zero tail, prefetch kept.
__global__ __launch_bounds__(256, 2) void attn_kernel(
        const unsigned short* __restrict__ Qf,   // [8192][1024] bf16 (x SCL)
        const unsigned short* __restrict__ Kf,   // [8192][1024] bf16
        const unsigned short* __restrict__ VT,   // [64*64][2048] bf16, key-permuted
        const float* __restrict__ maskl,         // [4][2048], pre-scaled by LOG2E
        float* __restrict__ out)                 // [4][2048][1024]
{
    __shared__ __align__(16) unsigned short Ksh[2 * 128 * 64]; // 2 x (128 keys x 64 d)
    __shared__ __align__(16) unsigned short Vsh[2 * 64 * 128]; // 2 x (64 d x 128 keys)
    __shared__ __align__(16) float Msh[2 * 132];               // 2 x mask tile
    __shared__ __align__(16) float Lsh[256];                   // 1/l(q), end only

    const int tid  = threadIdx.x;
    const int lane = tid & 63;
    const int wv   = tid >> 6;
    const int q32  = lane & 31;
    const int hi   = lane >> 5;
    const int bh   = blockIdx.x & 63;
    const int qt   = blockIdx.x >> 6;                // 0..7
    const int b    = bh >> 4;
    const int h    = bh & 15;
    const int q0   = qt * 256 + wv * 64;             // wave owns 64 queries
    const int sw   = q32 & 7;                        // per-lane XOR swizzle key

    // Q as B-operand fragments for both q-subtiles, hoisted out of K-loop
    short8 bQ0[4], bQ1[4];
#pragma unroll
    for (int ks = 0; ks < 4; ++ks) {
        bQ0[ks] = *(const short8*)(Qf + (size_t)(b * 2048 + q0 + q32) * 1024
                                      + h * 64 + ks * 16 + hi * 8);
        bQ1[ks] = *(const short8*)(Qf + (size_t)(b * 2048 + q0 + 32 + q32) * 1024
                                      + h * 64 + ks * 16 + hi * 8);
    }

    floatx16 accO00 = 0.0f, accO01 = 0.0f;   // qsub0: d-lo, d-hi
    floatx16 accO10 = 0.0f, accO11 = 0.0f;   // qsub1
    float l0 = 0.0f, l1 = 0.0f;

    const unsigned short* gK = Kf + (size_t)(b * 2048) * 1024 + h * 64;
    const unsigned short* gV = VT + (size_t)(bh * 64) * 2048;
    const float* mrow = maskl + b * 2048;

    // hoisted, loop-invariant LDS read bases (imm offsets inside the loop)
    const unsigned short* kb4[4];
    const unsigned short* vb4[4];
#pragma unroll
    for (int ks = 0; ks < 4; ++ks) {
        const int cs = (2 * ks + hi) ^ sw;
        kb4[ks] = Ksh + q32 * 64 + cs * 8;
        vb4[ks] = Vsh + q32 * 128 + cs * 8;
    }

    // staging lane maps
    const int krr = lane >> 3;                 // K: row-in-group (8 rows/GLP)
    const int kcs = lane & 7;                  // K: slot
    const int vrr = lane >> 4;                 // V: row-in-group (4 rows/GLP)
    const int vcs = lane & 15;                 // V: slot (16/row)

    // stage tile (kbn) into buffer at ushort offset so / mask float offset mo
    auto STAGE = [&](int kbn, int so, int mo) {
#pragma unroll
        for (int s = 0; s < 4; ++s) {
            const int seg = wv * 4 + s;                       // 0..15
            const int rK  = seg * 8 + krr;                    // key row 0..127
            const int cK  = kcs ^ (rK & 7);
            GLP(gK + (size_t)(kbn + rK) * 1024 + cK * 8, Ksh + so + seg * 512);
            const int rV  = seg * 4 + vrr;                    // d row 0..63
            const int cV  = vcs ^ (rV & 7);
            GLP(gV + (size_t)rV * 2048 + kbn + cV * 8, Vsh + so + seg * 512);
        }
        if (tid < 32) GLP(mrow + kbn + lane * 4, Msh + mo);
    };

    // one KV tile: prefetch t+1 into the other buffer, compute t, drain+barrier
    auto TILE = [&](int kb, int ro, int mo, int so, int smo) {
        if (kb + 128 < 2048) STAGE(kb + 128, so, smo);
        const float* mb = Msh + mo + hi * 4;
#pragma unroll 1
        for (int half = 0; half < 2; ++half) {
#pragma unroll
            for (int mt = 0; mt < 2; ++mt) {
                // --- K frags for this 32-key subtile (shared by both q-subtiles) ---
                short8 aK[4];
#pragma unroll
                for (int ks = 0; ks < 4; ++ks)
                    aK[ks] = *(const short8*)(kb4[ks] + ro + half * 4096 + mt * 2048);
                // --- S^T MFMAs: A = K (m=key 32), B = Q' (n=query 32), C = mask ---
                floatx16 s0, s1;
#pragma unroll
                for (int a = 0; a < 4; ++a) {
                    float4 mv4 = *(const float4*)(mb + half * 64 + mt * 32 + a * 8);
                    s0[a * 4 + 0] = mv4.x; s0[a * 4 + 1] = mv4.y;
                    s0[a * 4 + 2] = mv4.z; s0[a * 4 + 3] = mv4.w;
                    s1[a * 4 + 0] = mv4.x; s1[a * 4 + 1] = mv4.y;
                    s1[a * 4 + 2] = mv4.z; s1[a * 4 + 3] = mv4.w;
                }
                __builtin_amdgcn_s_setprio(1);
#pragma unroll
                for (int ks = 0; ks < 4; ++ks)
                    s0 = __builtin_amdgcn_mfma_f32_32x32x16_bf16(aK[ks], bQ0[ks], s0, 0, 0, 0);
#pragma unroll
                for (int ks = 0; ks < 4; ++ks)
                    s1 = __builtin_amdgcn_mfma_f32_32x32x16_bf16(aK[ks], bQ1[ks], s1, 0, 0, 0);
                __builtin_amdgcn_s_setprio(0);
                // --- exp/pack both q-subtiles (s0, s1, aK die here) ---
                unsigned u0[8], u1[8];
#pragma unroll
                for (int a = 0; a < 4; ++a) {
                    float p0 = EXP2(s0[a * 4 + 0]);
                    float p1 = EXP2(s0[a * 4 + 1]);
                    float p2 = EXP2(s0[a * 4 + 2]);
                    float p3 = EXP2(s0[a * 4 + 3]);
                    l0 += (p0 + p1) + (p2 + p3);
                    u0[2 * a]     = pack2bf(p0, p1);
                    u0[2 * a + 1] = pack2bf(p2, p3);
                }
#pragma unroll
                for (int a = 0; a < 4; ++a) {
                    float p0 = EXP2(s1[a * 4 + 0]);
                    float p1 = EXP2(s1[a * 4 + 1]);
                    float p2 = EXP2(s1[a * 4 + 2]);
                    float p3 = EXP2(s1[a * 4 + 3]);
                    l1 += (p0 + p1) + (p2 + p3);
                    u1[2 * a]     = pack2bf(p0, p1);
                    u1[2 * a + 1] = pack2bf(p2, p3);
                }
                // --- V frags for this key-subtile (shared by both q-subtiles) ---
                short8 bV00 = *(const short8*)(vb4[mt * 2 + 0] + ro + half * 64);
                short8 bV01 = *(const short8*)(vb4[mt * 2 + 0] + ro + 4096 + half * 64);
                short8 bV10 = *(const short8*)(vb4[mt * 2 + 1] + ro + half * 64);
                short8 bV11 = *(const short8*)(vb4[mt * 2 + 1] + ro + 4096 + half * 64);
                // --- PV MFMAs ---
                union { unsigned uu[4]; short8 s; } aP;
                __builtin_amdgcn_s_setprio(1);
                aP.uu[0] = u0[0]; aP.uu[1] = u0[1]; aP.uu[2] = u0[2]; aP.uu[3] = u0[3];
                accO00 = __builtin_amdgcn_mfma_f32_32x32x16_bf16(aP.s, bV00, accO00, 0, 0, 0);
                accO01 = __builtin_amdgcn_mfma_f32_32x32x16_bf16(aP.s, bV01, accO01, 0, 0, 0);
                aP.uu[0] = u0[4]; aP.uu[1] = u0[5]; aP.uu[2] = u0[6]; aP.uu[3] = u0[7];
                accO00 = __builtin_amdgcn_mfma_f32_32x32x16_bf16(aP.s, bV10, accO00, 0, 0, 0);
                accO01 = __builtin_amdgcn_mfma_f32_32x32x16_bf16(aP.s, bV11, accO01, 0, 0, 0);
                aP.uu[0] = u1[0]; aP.uu[1] = u1[1]; aP.uu[2] = u1[2]; aP.uu[3] = u1[3];
                accO10 = __builtin_amdgcn_mfma_f32_32x32x16_bf16(aP.s, bV00, accO10, 0, 0, 0);
                accO11 = __builtin_amdgcn_mfma_f32_32x32x16_bf16(aP.s, bV01, accO11, 0, 0, 0);
                aP.uu[0] = u1[4]; aP.uu[1] = u1[5]; aP.uu[2] = u1[6]; aP.uu[3] = u1[7];
                accO10 = __builtin_amdgcn_mfma_f32_32x32x16_bf16(aP.s, bV10, accO10, 0, 0, 0);
                accO11 = __builtin_amdgcn_mfma_f32_32x32x16_bf16(aP.s, bV11, accO11, 0, 0, 0);
                __builtin_amdgcn_s_setprio(0);
            }
        }
        // prefetch (issued before ~4100 cyc of compute) has landed; drain is cheap.
        // Barrier also fences: everyone done reading buffer ro before next stage.
        asm volatile("s_waitcnt vmcnt(0) lgkmcnt(0)" ::: "memory");
        __builtin_amdgcn_s_barrier();
    };

    // prologue: stage tile 0 into buffer 0
    STAGE(0, 0, 0);
    asm volatile("s_waitcnt vmcnt(0)" ::: "memory");
    __builtin_amdgcn_s_barrier();

#pragma unroll 1
    for (int kb2 = 0; kb2 < 2048; kb2 += 256) {
        TILE(kb2,       0,    0,   8192, 132);   // read buf0, stage -> buf1
        TILE(kb2 + 128, 8192, 132, 0,    0);     // read buf1, stage -> buf0
    }

    // l(q): combine the two hi-halves, redistribute to row-indexed layout via Lsh
    l0 += __shfl_xor(l0, 32, 64);
    l1 += __shfl_xor(l1, 32, 64);
    if (lane < 32) {
        Lsh[wv * 64 + q32]      = 1.0f / l0;
        Lsh[wv * 64 + 32 + q32] = 1.0f / l1;
    }
    // wave-synchronous: same wave wrote Lsh; compiler orders via lgkmcnt
#pragma unroll
    for (int g = 0; g < 4; ++g) {
        float4 i0 = *(const float4*)(Lsh + wv * 64 + g * 8 + hi * 4);
        float4 i1 = *(const float4*)(Lsh + wv * 64 + 32 + g * 8 + hi * 4);
#pragma unroll
        for (int rr = 0; rr < 4; ++rr) {
            const int r   = g * 4 + rr;
            const int row = rr + 8 * g + 4 * hi;
            const float l0v = (rr == 0) ? i0.x : (rr == 1) ? i0.y
                            : (rr == 2) ? i0.z : i0.w;
            const float l1v = (rr == 0) ? i1.x : (rr == 1) ? i1.y
                            : (rr == 2) ? i1.z : i1.w;
            float* op0 = out + (size_t)(b * 2048 + q0 + row) * 1024 + h * 64 + q32;
            float* op1 = out + (size_t)(b * 2048 + q0 + 32 + row) * 1024 + h * 64 + q32;
            op0[0]  = accO00[r] * l0v;
            op0[32] = accO01[r] * l0v;
            op1[0]  = accO10[r] * l1v;
            op1[32] = accO11[r] * l1v;
        }
    }
}

// ---------------- launch ----------------
extern "C" void kernel_launch(void* const* d_in, const int* in_sizes, int n_in,
                              void* d_out, int out_size, void* d_ws, size_t ws_size,
                              hipStream_t stream) {
    const float* X    = (const float*)d_in[0];
    const float* mask = (const float*)d_in[1];
    const float* Wq   = (const float*)d_in[2];
    const float* bq   = (const float*)d_in[3];
    const float* Wk   = (const float*)d_in[4];
    const float* bk   = (const float*)d_in[5];
    const float* Wv   = (const float*)d_in[6];
    const float* bv   = (const float*)d_in[7];
    float* out = (float*)d_out;

    char* ws = (char*)d_ws;
    unsigned short* xb  = (unsigned short*)(ws);                // 8192*1024 bf16 (16MB)
    unsigned short* wb  = (unsigned short*)(ws + 16777216);     // 3072*1024 bf16 (6MB)
    unsigned short* qf  = (unsigned short*)(ws + 23068672);     // [8192][1024] (16MB)
    unsigned short* kf  = (unsigned short*)(ws + 39845888);     // [8192][1024] (16MB)
    unsigned short* vtb = (unsigned short*)(ws + 56623104);     // [64*64][2048] (16MB)
    float*          ml  = (float*)(ws + 73400320);              // [4][2048] (32KB)

    cvt_all<<<11272, 256, 0, stream>>>(X, Wq, Wk, Wv, mask, xb, wb, ml);

    qkv_gemm<<<dim3(64, 24), 256, 0, stream>>>(xb, wb, bq, bk, bv, qf, kf, vtb);

    attn_kernel<<<512, 256, 0, stream>>>(qf, kf, vtb, ml, out);
}